// Round 6
// baseline (1419.625 us; speedup 1.0000x reference)
//
#include <hip/hip_runtime.h>
#include <hip/hip_bf16.h>

typedef __attribute__((ext_vector_type(8))) short short8;
typedef __attribute__((ext_vector_type(4))) short short4_;
typedef __attribute__((ext_vector_type(4))) float f32x4;

#define MFMA16(a,b,c) __builtin_amdgcn_mfma_f32_16x16x32_bf16((a),(b),(c),0,0,0)

// LDS-only barrier: does NOT drain vmcnt -> streamed weight loads stay in
// flight. Cross-wave deps inside the step loop are LDS-only (globals are
// read-only weights; register prefetches are waited via compiler vmcnt).
#define BAR() do {                                         \
  __builtin_amdgcn_sched_barrier(0);                       \
  asm volatile("s_waitcnt lgkmcnt(0)" ::: "memory");       \
  __builtin_amdgcn_s_barrier();                            \
  __builtin_amdgcn_sched_barrier(0);                       \
} while (0)

// ---- helpers ----------------------------------------------------------------
__device__ __forceinline__ short f2bf(float f){
  union { float f; unsigned u; } v; v.f = f;
  unsigned u = v.u;
  u = u + 0x7fffu + ((u >> 16) & 1u);   // RNE
  return (short)(u >> 16);
}

__device__ __forceinline__ float gelu_f(float x){
  float x2 = x * x;
  float t  = __builtin_fmaf(0.044715f, x2, 1.0f);
  float u  = 2.30211416f * x * t;
  float e  = __builtin_exp2f(u);
  float r  = __builtin_amdgcn_rcpf(e + 1.0f);
  return x * (1.0f - r);
}

// ---- prep: transpose + bf16-blocked weight layouts into ws ------------------
// blocked layout: element slot = ((ntile*NKS + ks)*64 + lane)*8 + j
//   holds W[k = ks*32 + (lane>>4)*8 + j][n = ntile*16 + (lane&15)]  (i.e. W^T)
__global__ void prep_kernel(
    const float* __restrict__ rW1, const float* __restrict__ rW2,
    const float* __restrict__ fW1, const float* __restrict__ fW2,
    const float* __restrict__ mW1,
    short* __restrict__ w1t_all, short* __restrict__ w2t_all,
    short* __restrict__ mw1t)
{
  int id = blockIdx.x * 256 + threadIdx.x;
  short8 v;
  if (id < 32768) {                       // W1a^T: 2 nets x 16 nt x 16 ks x 64
    int l = id & 63, ks = (id >> 6) & 15, nt = (id >> 10) & 15, net = id >> 14;
    const float* W = net ? fW1 : rW1;     // [513][256]
    int n  = nt * 16 + (l & 15);
    int k0 = ks * 32 + (l >> 4) * 8;
    #pragma unroll
    for (int j = 0; j < 8; ++j) v[j] = f2bf(W[(size_t)(k0 + j) * 256 + n]);
    *(short8*)(w1t_all + (size_t)id * 8) = v;
  } else if (id < 65536) {                // W2^T: 2 nets x 32 nt x 8 ks x 64
    int id2 = id - 32768;
    int l = id2 & 63, ks = (id2 >> 6) & 7, nt = (id2 >> 9) & 31, net = id2 >> 14;
    const float* W = net ? fW2 : rW2;     // [256][512]
    int n  = nt * 16 + (l & 15);
    int k0 = ks * 32 + (l >> 4) * 8;
    #pragma unroll
    for (int j = 0; j < 8; ++j) v[j] = f2bf(W[(size_t)(k0 + j) * 512 + n]);
    *(short8*)(w2t_all + (size_t)id2 * 8) = v;
  } else {                                // mlpW1^T: 64 nt x 32 ks x 64
    int id3 = id - 65536;
    int l = id3 & 63, ks = (id3 >> 6) & 31, nt = id3 >> 11;
    int n  = nt * 16 + (l & 15);
    int k0 = ks * 32 + (l >> 4) * 8;
    #pragma unroll
    for (int j = 0; j < 8; ++j) v[j] = f2bf(mW1[(size_t)(k0 + j) * 1024 + n]);
    *(short8*)(mw1t + (size_t)id3 * 8) = v;
  }
}

// ---- fused persistent ODE integrator ---------------------------------------
// 256 wgs; net = blk&1 (XCD-segregated under blk%8 round-robin), rows blk>>1.
// z in f32 MFMA accumulators across all 100 steps.
//
// SPILL-PROOF arch-register budget (worst phase, non-accumulator):
//   W1 rolling slots 16 + q-banks 32 + b temps + addr/GELU temps ~45  -> ~95.
// Accumulators zacc(64) + hacc(32) are AGPR-eligible. NO weight reg caches.
#define LDW1(nt, ks) (*(const short8*)(w1t + ((size_t)(((2 * w + (nt)) * 16 + (ks)) * 64 + l) * 8)))
#define LDW2(nt, ks) (*(const short8*)(w2t + ((size_t)(((4 * w + (nt)) * 8  + (ks)) * 64 + l) * 8)))

__global__ __launch_bounds__(512) __attribute__((amdgpu_waves_per_eu(2)))
void ode_kernel(
    const float* __restrict__ z0,
    const short* __restrict__ w1t_all,
    const short* __restrict__ w2t_all,
    const float* __restrict__ rW1, const float* __restrict__ rb1, const float* __restrict__ rb2,
    const float* __restrict__ fW1, const float* __restrict__ fb1, const float* __restrict__ fb2,
    short* __restrict__ proj_all)
{
  __shared__ __align__(16) short zs[32768];   // 64 KB: z tile [64][512]
  __shared__ __align__(16) short hs[16384];   // 32 KB: h tile [64][256]
  __shared__ __align__(16) float cst[1024];   //  4 KB: b1 | W1t-row | -dt*b2

  const int blk = blockIdx.x;
  const int net = blk & 1;
  const int m0  = (blk >> 1) * 64;
  const int tid = threadIdx.x;
  const int w   = tid >> 6;       // wave 0..7
  const int l   = tid & 63;
  const int l4  = l & 15;
  const int g   = l >> 4;         // 0..3

  const short* w1t = w1t_all + net * 131072;
  const short* w2t = w2t_all + net * 131072;
  const float* b1p = net ? fb1 : rb1;
  const float* b2p = net ? fb2 : rb2;
  const float* w1r = (net ? fW1 : rW1) + 512 * 256;   // t-row of W1
  short* proj = proj_all + (size_t)net * (8192 * 512);

  // ---- constants into LDS ----
  if (tid < 256)       cst[tid] = b1p[tid];
  else                 cst[tid] = w1r[tid - 256];
  cst[512 + tid] = -0.01f * b2p[tid];

  // ---- z accumulator ----
  f32x4 zacc[4][4];
  #pragma unroll
  for (int nt = 0; nt < 4; ++nt)
    #pragma unroll
    for (int mt = 0; mt < 4; ++mt)
      zacc[nt][mt] = *(const f32x4*)(z0 + (size_t)(m0 + 16 * mt + l4) * 512
                                        + (64 * w + 16 * nt + 4 * g));

  // rolling prefetch slots (named scalars, reload-in-place)
  short8 pA0, pB0, pA1, pB1;        // GEMM1 A (both ntiles), depth 2
  short8 q00, q01, q02, q03;        // GEMM2 A bank 0 (4 ntiles)
  short8 q10, q11, q12, q13;        // GEMM2 A bank 1

// one fused GEMM1 k-slice: b shared by BOTH ntiles; POST = refill stmts
#define G1F(ks, pa, pb, ...) do {                                              \
    _Pragma("unroll")                                                          \
    for (int mt = 0; mt < 4; ++mt){                                            \
      int m  = 16 * mt + l4;                                                   \
      int kk = (ks) * 32 + 8 * g;                                              \
      short8 b = *(const short8*)((const char*)zs +                            \
                   (m * 1024 + ((kk * 2) ^ ((m & 7) << 4))));                  \
      hacc[0][mt] = MFMA16(pa, b, hacc[0][mt]);                                \
      hacc[1][mt] = MFMA16(pb, b, hacc[1][mt]);                                \
    }                                                                          \
    __VA_ARGS__;                                                               \
  } while (0)

// one GEMM2 k-slice (all 4 z-ntiles); POST = refill stmts
#define G2K(ks, qa, qb, qc, qd, ...) do {                                      \
    _Pragma("unroll")                                                          \
    for (int mt = 0; mt < 4; ++mt){                                            \
      int m  = 16 * mt + l4;                                                   \
      int kk = (ks) * 32 + 8 * g;                                              \
      short8 b = *(const short8*)((const char*)hs +                            \
                   (m * 512 + ((kk * 2) ^ ((m & 7) << 4))));                   \
      zacc[0][mt] = MFMA16(qa, b, zacc[0][mt]);                                \
      zacc[1][mt] = MFMA16(qb, b, zacc[1][mt]);                                \
      zacc[2][mt] = MFMA16(qc, b, zacc[2][mt]);                                \
      zacc[3][mt] = MFMA16(qd, b, zacc[3][mt]);                                \
    }                                                                          \
    __VA_ARGS__;                                                               \
  } while (0)

// GELU + h-store for ntile NT from hacc[NT]
#define GELU_STORE(NT) do {                                                    \
    f32x4 b1q = *(const f32x4*)&cst[32 * w + 16 * (NT) + 4 * g];               \
    f32x4 w1q = *(const f32x4*)&cst[256 + 32 * w + 16 * (NT) + 4 * g];         \
    _Pragma("unroll")                                                          \
    for (int mt = 0; mt < 4; ++mt){                                            \
      int m = 16 * mt + l4;                                                    \
      short4_ pk;                                                              \
      _Pragma("unroll")                                                        \
      for (int r = 0; r < 4; ++r){                                             \
        float x = hacc[NT][mt][r] + __builtin_fmaf(tw, w1q[r], b1q[r]);        \
        pk[r] = f2bf(-0.01f * gelu_f(x));                                      \
      }                                                                        \
      int nq = 32 * w + 16 * (NT) + 4 * g;                                     \
      int byte = m * 512 + ((nq * 2) ^ ((m & 7) << 4));                        \
      *(short4_*)((char*)hs + byte) = pk;                                      \
    }                                                                          \
  } while (0)

  for (int i = 0; i < 100; ++i){
    float tw = 1.0f - 0.01f * (float)i;

    // prefetch GEMM1 ks 0,1 for both ntiles (flies during z-store + barrier)
    pA0 = LDW1(0, 0); pB0 = LDW1(1, 0);
    pA1 = LDW1(0, 1); pB1 = LDW1(1, 1);

    // ---- store z (bf16) into LDS, swizzled ----
    #pragma unroll
    for (int nt = 0; nt < 4; ++nt)
      #pragma unroll
      for (int mt = 0; mt < 4; ++mt){
        int m  = 16 * mt + l4;
        int kq = 64 * w + 16 * nt + 4 * g;
        short4_ pk;
        #pragma unroll
        for (int r = 0; r < 4; ++r) pk[r] = f2bf(zacc[nt][mt][r]);
        int byte = m * 1024 + ((kq * 2) ^ ((m & 7) << 4));
        *(short4_*)((char*)zs + byte) = pk;
      }
    BAR();

    // ---- GEMM1 (fused): hT[n][m] = W1a^T * z^T, K=512, b shared over 2 nt --
    f32x4 hacc[2][4];
    #pragma unroll
    for (int nt = 0; nt < 2; ++nt)
      #pragma unroll
      for (int mt = 0; mt < 4; ++mt) hacc[nt][mt] = (f32x4){0.f,0.f,0.f,0.f};

    G1F( 0, pA0, pB0, pA0 = LDW1(0, 2);  pB0 = LDW1(1, 2));
    G1F( 1, pA1, pB1, pA1 = LDW1(0, 3);  pB1 = LDW1(1, 3));
    G1F( 2, pA0, pB0, pA0 = LDW1(0, 4);  pB0 = LDW1(1, 4));
    G1F( 3, pA1, pB1, pA1 = LDW1(0, 5);  pB1 = LDW1(1, 5));
    G1F( 4, pA0, pB0, pA0 = LDW1(0, 6);  pB0 = LDW1(1, 6));
    G1F( 5, pA1, pB1, pA1 = LDW1(0, 7);  pB1 = LDW1(1, 7));
    G1F( 6, pA0, pB0, pA0 = LDW1(0, 8);  pB0 = LDW1(1, 8));
    G1F( 7, pA1, pB1, pA1 = LDW1(0, 9);  pB1 = LDW1(1, 9));
    G1F( 8, pA0, pB0, pA0 = LDW1(0,10);  pB0 = LDW1(1,10));
    G1F( 9, pA1, pB1, pA1 = LDW1(0,11);  pB1 = LDW1(1,11));
    G1F(10, pA0, pB0, pA0 = LDW1(0,12);  pB0 = LDW1(1,12));
    G1F(11, pA1, pB1, pA1 = LDW1(0,13);  pB1 = LDW1(1,13));
    G1F(12, pA0, pB0, pA0 = LDW1(0,14);  pB0 = LDW1(1,14));
    G1F(13, pA1, pB1, pA1 = LDW1(0,15);  pB1 = LDW1(1,15));
    // tails: refill GEMM2 banks (fly during GELU + h-store + barrier)
    G1F(14, pA0, pB0, q00 = LDW2(0,0); q01 = LDW2(1,0); q02 = LDW2(2,0); q03 = LDW2(3,0));
    G1F(15, pA1, pB1, q10 = LDW2(0,1); q11 = LDW2(1,1); q12 = LDW2(2,1); q13 = LDW2(3,1));

    // ---- GELU, scale by -dt, write h (bf16) into hs ----
    GELU_STORE(0);
    GELU_STORE(1);
    BAR();

    // ---- GEMM2: z += W2^T * h^T  (K=256), two rolling 4-wide banks ----
    G2K(0, q00, q01, q02, q03, q00=LDW2(0,2); q01=LDW2(1,2); q02=LDW2(2,2); q03=LDW2(3,2));
    G2K(1, q10, q11, q12, q13, q10=LDW2(0,3); q11=LDW2(1,3); q12=LDW2(2,3); q13=LDW2(3,3));
    G2K(2, q00, q01, q02, q03, q00=LDW2(0,4); q01=LDW2(1,4); q02=LDW2(2,4); q03=LDW2(3,4));
    G2K(3, q10, q11, q12, q13, q10=LDW2(0,5); q11=LDW2(1,5); q12=LDW2(2,5); q13=LDW2(3,5));
    G2K(4, q00, q01, q02, q03, q00=LDW2(0,6); q01=LDW2(1,6); q02=LDW2(2,6); q03=LDW2(3,6));
    G2K(5, q10, q11, q12, q13, q10=LDW2(0,7); q11=LDW2(1,7); q12=LDW2(2,7); q13=LDW2(3,7));
    G2K(6, q00, q01, q02, q03, );
    G2K(7, q10, q11, q12, q13, );

    // ---- -dt*b2 bias ----
    #pragma unroll
    for (int nt = 0; nt < 4; ++nt){
      f32x4 b2q = *(const f32x4*)&cst[512 + 64 * w + 16 * nt + 4 * g];
      #pragma unroll
      for (int mt = 0; mt < 4; ++mt)
        #pragma unroll
        for (int r = 0; r < 4; ++r)
          zacc[nt][mt][r] += b2q[r];
    }
  }
#undef G1F
#undef G2K
#undef GELU_STORE

  // ---- write projection (bf16) ----
  #pragma unroll
  for (int nt = 0; nt < 4; ++nt)
    #pragma unroll
    for (int mt = 0; mt < 4; ++mt){
      int mg = m0 + 16 * mt + l4;
      int nq = 64 * w + 16 * nt + 4 * g;
      short4_ pk;
      #pragma unroll
      for (int r = 0; r < 4; ++r) pk[r] = f2bf(zacc[nt][mt][r]);
      *(short4_*)(proj + (size_t)mg * 512 + nq) = pk;
    }
}

// ---- classifier: logits = gelu([real||fake] @ W1 + b1) @ W2 + b2 -----------
__global__ __launch_bounds__(512, 2) void cls_kernel(
    const short* __restrict__ mw1t,
    const short* __restrict__ proj_all,
    const float* __restrict__ mb1,
    const float* __restrict__ mw2,
    const float* __restrict__ mb2,
    float* __restrict__ out)
{
  __shared__ __align__(16) float sb1[1024];
  __shared__ __align__(16) float sw2[2048];
  __shared__ __align__(16) float sred[2048];

  const int blk = blockIdx.x;
  const int m0  = blk * 32;
  const int tid = threadIdx.x;
  const int w = tid >> 6, l = tid & 63, l4 = l & 15, g = l >> 4;

  #pragma unroll
  for (int j = 0; j < 2; ++j) sb1[tid + 512 * j] = mb1[tid + 512 * j];
  #pragma unroll
  for (int j = 0; j < 4; ++j) sw2[tid + 512 * j] = mw2[tid + 512 * j];
  __syncthreads();

  float lacc[2][2] = {{0.f, 0.f}, {0.f, 0.f}};

  for (int rnd = 0; rnd < 4; ++rnd){
    f32x4 hacc[2][2];
    #pragma unroll
    for (int nt = 0; nt < 2; ++nt)
      #pragma unroll
      for (int mt = 0; mt < 2; ++mt)
        hacc[nt][mt] = (f32x4){0.f, 0.f, 0.f, 0.f};

    #pragma unroll
    for (int ks = 0; ks < 32; ++ks){
      int gnt0 = rnd * 16 + 2 * w;
      short8 a0 = *(const short8*)(mw1t + ((size_t)((gnt0    ) * 32 + ks) * 64 + l) * 8);
      short8 a1 = *(const short8*)(mw1t + ((size_t)((gnt0 + 1) * 32 + ks) * 64 + l) * 8);
      int k = ks * 32 + 8 * g;   // combined-dim index; uniform side per ks
      const short* src = (k < 512) ? (proj_all + k)
                                   : (proj_all + ((size_t)8192 * 512 - 512) + k);
      #pragma unroll
      for (int mt = 0; mt < 2; ++mt){
        int mg = m0 + 16 * mt + l4;
        short8 b = *(const short8*)(src + (size_t)mg * 512);
        hacc[0][mt] = MFMA16(a0, b, hacc[0][mt]);
        hacc[1][mt] = MFMA16(a1, b, hacc[1][mt]);
      }
    }
    #pragma unroll
    for (int nt = 0; nt < 2; ++nt){
      int nq = (rnd * 16 + 2 * w + nt) * 16 + 4 * g;
      f32x4 bb = *(const f32x4*)(sb1 + nq);
      #pragma unroll
      for (int r = 0; r < 4; ++r){
        float w2c0 = sw2[(nq + r) * 2 + 0];
        float w2c1 = sw2[(nq + r) * 2 + 1];
        #pragma unroll
        for (int mt = 0; mt < 2; ++mt){
          float x  = hacc[nt][mt][r] + bb[r];
          float gv = gelu_f(x);
          lacc[mt][0] = __builtin_fmaf(gv, w2c0, lacc[mt][0]);
          lacc[mt][1] = __builtin_fmaf(gv, w2c1, lacc[mt][1]);
        }
      }
    }
  }

  int part = w * 4 + g;  // 0..31
  #pragma unroll
  for (int mt = 0; mt < 2; ++mt)
    #pragma unroll
    for (int c = 0; c < 2; ++c)
      sred[((16 * mt + l4) * 2 + c) * 32 + part] = lacc[mt][c];
  __syncthreads();
  if (tid < 64){
    int m = tid >> 1, c = tid & 1;
    float s = 0.f;
    #pragma unroll
    for (int p2 = 0; p2 < 32; ++p2) s += sred[(m * 2 + c) * 32 + p2];
    out[(size_t)(m0 + m) * 2 + c] = s + mb2[c];
  }
}

// ---- launch -----------------------------------------------------------------
extern "C" void kernel_launch(void* const* d_in, const int* in_sizes, int n_in,
                              void* d_out, int out_size, void* d_ws, size_t ws_size,
                              hipStream_t stream)
{
  const float* z0  = (const float*)d_in[0];
  const float* rW1 = (const float*)d_in[1];
  const float* rb1 = (const float*)d_in[2];
  const float* rW2 = (const float*)d_in[3];
  const float* rb2 = (const float*)d_in[4];
  const float* fW1 = (const float*)d_in[5];
  const float* fb1 = (const float*)d_in[6];
  const float* fW2 = (const float*)d_in[7];
  const float* fb2 = (const float*)d_in[8];
  const float* mW1 = (const float*)d_in[9];
  const float* mb1 = (const float*)d_in[10];
  const float* mW2 = (const float*)d_in[11];
  const float* mb2 = (const float*)d_in[12];
  float* out = (float*)d_out;

  char* ws = (char*)d_ws;
  short* w1t_all = (short*)(ws);                 //   524288 B (2 nets)
  short* w2t_all = (short*)(ws + 524288);        //   524288 B (2 nets)
  short* mw1t    = (short*)(ws + 1048576);       //  2097152 B
  short* proj    = (short*)(ws + 3145728);       // 16777216 B (real||fake, bf16)

  prep_kernel<<<768, 256, 0, stream>>>(rW1, rW2, fW1, fW2, mW1, w1t_all, w2t_all, mw1t);
  ode_kernel<<<256, 512, 0, stream>>>(z0, w1t_all, w2t_all,
                                      rW1, rb1, rb2, fW1, fb1, fb2, proj);
  cls_kernel<<<256, 512, 0, stream>>>(mw1t, proj, mb1, mW2, mb2, out);
}

// Round 7
// 1034.706 us; speedup vs baseline: 1.3720x; 1.3720x over previous
//
#include <hip/hip_runtime.h>
#include <hip/hip_bf16.h>

typedef __attribute__((ext_vector_type(8))) short short8;
typedef __attribute__((ext_vector_type(4))) short short4_;
typedef __attribute__((ext_vector_type(4))) float f32x4;
typedef __attribute__((ext_vector_type(2))) unsigned int uint2_;

#define MFMA16(a,b,c) __builtin_amdgcn_mfma_f32_16x16x32_bf16((a),(b),(c),0,0,0)

// LDS-only barrier: does NOT drain vmcnt -> streamed weight loads stay in
// flight. Cross-wave deps inside the step loop are LDS-only.
#define BAR() do {                                         \
  __builtin_amdgcn_sched_barrier(0);                       \
  asm volatile("s_waitcnt lgkmcnt(0)" ::: "memory");       \
  __builtin_amdgcn_s_barrier();                            \
  __builtin_amdgcn_sched_barrier(0);                       \
} while (0)

// ---- helpers ----------------------------------------------------------------
__device__ __forceinline__ short f2bf(float f){
  union { float f; unsigned u; } v; v.f = f;
  unsigned u = v.u;
  u = u + 0x7fffu + ((u >> 16) & 1u);   // RNE
  return (short)(u >> 16);
}

// packed f32x2 -> bf16x2 (RNE), lo -> bits[15:0]
__device__ __forceinline__ unsigned cvt_pk_bf16(float lo, float hi){
  unsigned r;
  asm("v_cvt_pk_bf16_f32 %0, %1, %2" : "=v"(r) : "v"(lo), "v"(hi));
  return r;
}

__device__ __forceinline__ float gelu_f(float x){
  float x2 = x * x;
  float t  = __builtin_fmaf(0.044715f, x2, 1.0f);
  float u  = 2.30211416f * x * t;
  float e  = __builtin_exp2f(u);
  float r  = __builtin_amdgcn_rcpf(e + 1.0f);
  return x * (1.0f - r);
}

// ---- prep: transpose + bf16-blocked weight layouts into ws ------------------
// blocked layout: element slot = ((ntile*NKS + ks)*64 + lane)*8 + j
//   holds W[k = ks*32 + (lane>>4)*8 + j][n = ntile*16 + (lane&15)]  (i.e. W^T)
__global__ void prep_kernel(
    const float* __restrict__ rW1, const float* __restrict__ rW2,
    const float* __restrict__ fW1, const float* __restrict__ fW2,
    const float* __restrict__ mW1,
    short* __restrict__ w1t_all, short* __restrict__ w2t_all,
    short* __restrict__ mw1t)
{
  int id = blockIdx.x * 256 + threadIdx.x;
  short8 v;
  if (id < 32768) {                       // W1a^T: 2 nets x 16 nt x 16 ks x 64
    int l = id & 63, ks = (id >> 6) & 15, nt = (id >> 10) & 15, net = id >> 14;
    const float* W = net ? fW1 : rW1;     // [513][256]
    int n  = nt * 16 + (l & 15);
    int k0 = ks * 32 + (l >> 4) * 8;
    #pragma unroll
    for (int j = 0; j < 8; ++j) v[j] = f2bf(W[(size_t)(k0 + j) * 256 + n]);
    *(short8*)(w1t_all + (size_t)id * 8) = v;
  } else if (id < 65536) {                // W2^T: 2 nets x 32 nt x 8 ks x 64
    int id2 = id - 32768;
    int l = id2 & 63, ks = (id2 >> 6) & 7, nt = (id2 >> 9) & 31, net = id2 >> 14;
    const float* W = net ? fW2 : rW2;     // [256][512]
    int n  = nt * 16 + (l & 15);
    int k0 = ks * 32 + (l >> 4) * 8;
    #pragma unroll
    for (int j = 0; j < 8; ++j) v[j] = f2bf(W[(size_t)(k0 + j) * 512 + n]);
    *(short8*)(w2t_all + (size_t)id2 * 8) = v;
  } else {                                // mlpW1^T: 64 nt x 32 ks x 64
    int id3 = id - 65536;
    int l = id3 & 63, ks = (id3 >> 6) & 31, nt = id3 >> 11;
    int n  = nt * 16 + (l & 15);
    int k0 = ks * 32 + (l >> 4) * 8;
    #pragma unroll
    for (int j = 0; j < 8; ++j) v[j] = f2bf(mW1[(size_t)(k0 + j) * 1024 + n]);
    *(short8*)(mw1t + (size_t)id3 * 8) = v;
  }
}

// ---- fused persistent ODE integrator ---------------------------------------
// 256 wgs; net = blk&1 (XCD-segregated under blk%8 round-robin), rows blk>>1.
// z in f32 MFMA accumulators across all 100 steps.
//
// SPILL-PROOF phase-disjoint arch-register plan (non-accumulator):
//   GEMM1 phase: p-slots 32 + addr temps      (~75 total)
//   GELU  phase: q-bank0 32 + GELU temps      (~70 total)
//   GEMM2 phase: q-banks 32 + addr temps      (~70 total)
// zacc(64) + hacc(32) are MFMA accumulators (AGPR-eligible).
#define LDW1(nt, ks) (*(const short8*)(w1t + ((size_t)(((2 * w + (nt)) * 16 + (ks)) * 64 + l) * 8)))
#define LDW2(nt, ks) (*(const short8*)(w2t + ((size_t)(((4 * w + (nt)) * 8  + (ks)) * 64 + l) * 8)))

__global__ __launch_bounds__(512) __attribute__((amdgpu_waves_per_eu(2)))
void ode_kernel(
    const float* __restrict__ z0,
    const short* __restrict__ w1t_all,
    const short* __restrict__ w2t_all,
    const float* __restrict__ rW1, const float* __restrict__ rb1, const float* __restrict__ rb2,
    const float* __restrict__ fW1, const float* __restrict__ fb1, const float* __restrict__ fb2,
    short* __restrict__ proj_all)
{
  __shared__ __align__(16) short zs[32768];   // 64 KB: z tile [64][512]
  __shared__ __align__(16) short hs[16384];   // 32 KB: h tile [64][256]
  __shared__ __align__(16) float cst[1024];   //  4 KB: b1 | W1t-row | -dt*b2

  const int blk = blockIdx.x;
  const int net = blk & 1;
  const int m0  = (blk >> 1) * 64;
  const int tid = threadIdx.x;
  const int w   = tid >> 6;       // wave 0..7
  const int l   = tid & 63;
  const int l4  = l & 15;
  const int g   = l >> 4;         // 0..3

  const short* w1t = w1t_all + net * 131072;
  const short* w2t = w2t_all + net * 131072;
  const float* b1p = net ? fb1 : rb1;
  const float* b2p = net ? fb2 : rb2;
  const float* w1r = (net ? fW1 : rW1) + 512 * 256;   // t-row of W1
  short* proj = proj_all + (size_t)net * (8192 * 512);

  // ---- constants into LDS ----
  if (tid < 256)       cst[tid] = b1p[tid];
  else                 cst[tid] = w1r[tid - 256];
  cst[512 + tid] = -0.01f * b2p[tid];

  // ---- z accumulator ----
  f32x4 zacc[4][4];
  #pragma unroll
  for (int nt = 0; nt < 4; ++nt)
    #pragma unroll
    for (int mt = 0; mt < 4; ++mt)
      zacc[nt][mt] = *(const f32x4*)(z0 + (size_t)(m0 + 16 * mt + l4) * 512
                                        + (64 * w + 16 * nt + 4 * g));

  // rolling prefetch slots (named scalars, reload-in-place)
  short8 pA0, pB0, pA1, pB1;        // GEMM1 A (both ntiles), depth 2
  short8 q00, q01, q02, q03;        // GEMM2 A bank 0 (4 ntiles)
  short8 q10, q11, q12, q13;        // GEMM2 A bank 1

// one fused GEMM1 k-slice: b shared by BOTH ntiles; POST = refill stmts
#define G1F(ks, pa, pb, ...) do {                                              \
    _Pragma("unroll")                                                          \
    for (int mt = 0; mt < 4; ++mt){                                            \
      int m  = 16 * mt + l4;                                                   \
      int kk = (ks) * 32 + 8 * g;                                              \
      short8 b = *(const short8*)((const char*)zs +                            \
                   (m * 1024 + ((kk * 2) ^ ((m & 7) << 4))));                  \
      hacc[0][mt] = MFMA16(pa, b, hacc[0][mt]);                                \
      hacc[1][mt] = MFMA16(pb, b, hacc[1][mt]);                                \
    }                                                                          \
    __VA_ARGS__;                                                               \
  } while (0)

// one GEMM2 k-slice (all 4 z-ntiles); POST = refill stmts
#define G2K(ks, qa, qb, qc, qd, ...) do {                                      \
    _Pragma("unroll")                                                          \
    for (int mt = 0; mt < 4; ++mt){                                            \
      int m  = 16 * mt + l4;                                                   \
      int kk = (ks) * 32 + 8 * g;                                              \
      short8 b = *(const short8*)((const char*)hs +                            \
                   (m * 512 + ((kk * 2) ^ ((m & 7) << 4))));                   \
      zacc[0][mt] = MFMA16(qa, b, zacc[0][mt]);                                \
      zacc[1][mt] = MFMA16(qb, b, zacc[1][mt]);                                \
      zacc[2][mt] = MFMA16(qc, b, zacc[2][mt]);                                \
      zacc[3][mt] = MFMA16(qd, b, zacc[3][mt]);                                \
    }                                                                          \
    __VA_ARGS__;                                                               \
  } while (0)

// GELU + h-store for ntile NT from hacc[NT] (cvt_pk packed)
#define GELU_STORE(NT) do {                                                    \
    f32x4 b1q = *(const f32x4*)&cst[32 * w + 16 * (NT) + 4 * g];               \
    f32x4 w1q = *(const f32x4*)&cst[256 + 32 * w + 16 * (NT) + 4 * g];         \
    _Pragma("unroll")                                                          \
    for (int mt = 0; mt < 4; ++mt){                                            \
      int m = 16 * mt + l4;                                                    \
      float gv[4];                                                             \
      _Pragma("unroll")                                                        \
      for (int r = 0; r < 4; ++r){                                             \
        float x  = hacc[NT][mt][r] + __builtin_fmaf(tw, w1q[r], b1q[r]);       \
        float x2 = x * x;                                                      \
        float tt = __builtin_fmaf(0.044715f, x2, 1.0f);                        \
        float uu = 2.30211416f * x * tt;                                       \
        float ee = __builtin_exp2f(uu);                                        \
        float rr = __builtin_amdgcn_rcpf(ee + 1.0f);                           \
        float xs = -0.01f * x;                                                 \
        gv[r] = __builtin_fmaf(-xs, rr, xs);  /* xs*(1-rr) */                  \
      }                                                                        \
      uint2_ pk;                                                               \
      pk[0] = cvt_pk_bf16(gv[0], gv[1]);                                       \
      pk[1] = cvt_pk_bf16(gv[2], gv[3]);                                       \
      int nq = 32 * w + 16 * (NT) + 4 * g;                                     \
      int byte = m * 512 + ((nq * 2) ^ ((m & 7) << 4));                        \
      *(uint2_*)((char*)hs + byte) = pk;                                       \
    }                                                                          \
  } while (0)

  for (int i = 0; i < 100; ++i){
    float tw = 1.0f - 0.01f * (float)i;

    // prefetch GEMM1 ks 0,1 for both ntiles (flies during z-store + barrier)
    pA0 = LDW1(0, 0); pB0 = LDW1(1, 0);
    pA1 = LDW1(0, 1); pB1 = LDW1(1, 1);

    // ---- store z (bf16) into LDS, swizzled (cvt_pk packed) ----
    #pragma unroll
    for (int nt = 0; nt < 4; ++nt)
      #pragma unroll
      for (int mt = 0; mt < 4; ++mt){
        int m  = 16 * mt + l4;
        int kq = 64 * w + 16 * nt + 4 * g;
        uint2_ pk;
        pk[0] = cvt_pk_bf16(zacc[nt][mt][0], zacc[nt][mt][1]);
        pk[1] = cvt_pk_bf16(zacc[nt][mt][2], zacc[nt][mt][3]);
        int byte = m * 1024 + ((kq * 2) ^ ((m & 7) << 4));
        *(uint2_*)((char*)zs + byte) = pk;
      }
    BAR();

    // ---- GEMM1 (fused): hT[n][m] = W1a^T * z^T, K=512, b shared over 2 nt --
    f32x4 hacc[2][4];
    #pragma unroll
    for (int nt = 0; nt < 2; ++nt)
      #pragma unroll
      for (int mt = 0; mt < 4; ++mt) hacc[nt][mt] = (f32x4){0.f,0.f,0.f,0.f};

    G1F( 0, pA0, pB0, pA0 = LDW1(0, 2);  pB0 = LDW1(1, 2));
    G1F( 1, pA1, pB1, pA1 = LDW1(0, 3);  pB1 = LDW1(1, 3));
    G1F( 2, pA0, pB0, pA0 = LDW1(0, 4);  pB0 = LDW1(1, 4));
    G1F( 3, pA1, pB1, pA1 = LDW1(0, 5);  pB1 = LDW1(1, 5));
    G1F( 4, pA0, pB0, pA0 = LDW1(0, 6);  pB0 = LDW1(1, 6));
    G1F( 5, pA1, pB1, pA1 = LDW1(0, 7);  pB1 = LDW1(1, 7));
    G1F( 6, pA0, pB0, pA0 = LDW1(0, 8);  pB0 = LDW1(1, 8));
    G1F( 7, pA1, pB1, pA1 = LDW1(0, 9);  pB1 = LDW1(1, 9));
    G1F( 8, pA0, pB0, pA0 = LDW1(0,10);  pB0 = LDW1(1,10));
    G1F( 9, pA1, pB1, pA1 = LDW1(0,11);  pB1 = LDW1(1,11));
    G1F(10, pA0, pB0, pA0 = LDW1(0,12);  pB0 = LDW1(1,12));
    G1F(11, pA1, pB1, pA1 = LDW1(0,13);  pB1 = LDW1(1,13));
    G1F(12, pA0, pB0, pA0 = LDW1(0,14);  pB0 = LDW1(1,14));
    G1F(13, pA1, pB1, pA1 = LDW1(0,15);  pB1 = LDW1(1,15));
    G1F(14, pA0, pB0, );
    G1F(15, pA1, pB1, );
    // p-slots now dead.

    // q bank0: issued here, flies under BOTH GELU stores (p regs recycled)
    q00 = LDW2(0,0); q01 = LDW2(1,0); q02 = LDW2(2,0); q03 = LDW2(3,0);

    // ---- GELU, scale by -dt, write h (bf16) into hs ----
    GELU_STORE(0);
    GELU_STORE(1);

    // q bank1: flies under h-store drain + barrier + first G2K slice
    q10 = LDW2(0,1); q11 = LDW2(1,1); q12 = LDW2(2,1); q13 = LDW2(3,1);
    BAR();

    // ---- GEMM2: z += W2^T * h^T  (K=256), two rolling 4-wide banks ----
    G2K(0, q00, q01, q02, q03, q00=LDW2(0,2); q01=LDW2(1,2); q02=LDW2(2,2); q03=LDW2(3,2));
    G2K(1, q10, q11, q12, q13, q10=LDW2(0,3); q11=LDW2(1,3); q12=LDW2(2,3); q13=LDW2(3,3));
    G2K(2, q00, q01, q02, q03, q00=LDW2(0,4); q01=LDW2(1,4); q02=LDW2(2,4); q03=LDW2(3,4));
    G2K(3, q10, q11, q12, q13, q10=LDW2(0,5); q11=LDW2(1,5); q12=LDW2(2,5); q13=LDW2(3,5));
    G2K(4, q00, q01, q02, q03, q00=LDW2(0,6); q01=LDW2(1,6); q02=LDW2(2,6); q03=LDW2(3,6));
    G2K(5, q10, q11, q12, q13, q10=LDW2(0,7); q11=LDW2(1,7); q12=LDW2(2,7); q13=LDW2(3,7));
    G2K(6, q00, q01, q02, q03, );
    G2K(7, q10, q11, q12, q13, );

    // ---- -dt*b2 bias ----
    #pragma unroll
    for (int nt = 0; nt < 4; ++nt){
      f32x4 b2q = *(const f32x4*)&cst[512 + 64 * w + 16 * nt + 4 * g];
      #pragma unroll
      for (int mt = 0; mt < 4; ++mt)
        #pragma unroll
        for (int r = 0; r < 4; ++r)
          zacc[nt][mt][r] += b2q[r];
    }
  }
#undef G1F
#undef G2K
#undef GELU_STORE

  // ---- write projection (bf16) ----
  #pragma unroll
  for (int nt = 0; nt < 4; ++nt)
    #pragma unroll
    for (int mt = 0; mt < 4; ++mt){
      int mg = m0 + 16 * mt + l4;
      int nq = 64 * w + 16 * nt + 4 * g;
      uint2_ pk;
      pk[0] = cvt_pk_bf16(zacc[nt][mt][0], zacc[nt][mt][1]);
      pk[1] = cvt_pk_bf16(zacc[nt][mt][2], zacc[nt][mt][3]);
      *(uint2_*)(proj + (size_t)mg * 512 + nq) = pk;
    }
}

// ---- classifier: logits = gelu([real||fake] @ W1 + b1) @ W2 + b2 -----------
__global__ __launch_bounds__(512, 2) void cls_kernel(
    const short* __restrict__ mw1t,
    const short* __restrict__ proj_all,
    const float* __restrict__ mb1,
    const float* __restrict__ mw2,
    const float* __restrict__ mb2,
    float* __restrict__ out)
{
  __shared__ __align__(16) float sb1[1024];
  __shared__ __align__(16) float sw2[2048];
  __shared__ __align__(16) float sred[2048];

  const int blk = blockIdx.x;
  const int m0  = blk * 32;
  const int tid = threadIdx.x;
  const int w = tid >> 6, l = tid & 63, l4 = l & 15, g = l >> 4;

  #pragma unroll
  for (int j = 0; j < 2; ++j) sb1[tid + 512 * j] = mb1[tid + 512 * j];
  #pragma unroll
  for (int j = 0; j < 4; ++j) sw2[tid + 512 * j] = mw2[tid + 512 * j];
  __syncthreads();

  float lacc[2][2] = {{0.f, 0.f}, {0.f, 0.f}};

  for (int rnd = 0; rnd < 4; ++rnd){
    f32x4 hacc[2][2];
    #pragma unroll
    for (int nt = 0; nt < 2; ++nt)
      #pragma unroll
      for (int mt = 0; mt < 2; ++mt)
        hacc[nt][mt] = (f32x4){0.f, 0.f, 0.f, 0.f};

    #pragma unroll
    for (int ks = 0; ks < 32; ++ks){
      int gnt0 = rnd * 16 + 2 * w;
      short8 a0 = *(const short8*)(mw1t + ((size_t)((gnt0    ) * 32 + ks) * 64 + l) * 8);
      short8 a1 = *(const short8*)(mw1t + ((size_t)((gnt0 + 1) * 32 + ks) * 64 + l) * 8);
      int k = ks * 32 + 8 * g;   // combined-dim index; uniform side per ks
      const short* src = (k < 512) ? (proj_all + k)
                                   : (proj_all + ((size_t)8192 * 512 - 512) + k);
      #pragma unroll
      for (int mt = 0; mt < 2; ++mt){
        int mg = m0 + 16 * mt + l4;
        short8 b = *(const short8*)(src + (size_t)mg * 512);
        hacc[0][mt] = MFMA16(a0, b, hacc[0][mt]);
        hacc[1][mt] = MFMA16(a1, b, hacc[1][mt]);
      }
    }
    #pragma unroll
    for (int nt = 0; nt < 2; ++nt){
      int nq = (rnd * 16 + 2 * w + nt) * 16 + 4 * g;
      f32x4 bb = *(const f32x4*)(sb1 + nq);
      #pragma unroll
      for (int r = 0; r < 4; ++r){
        float w2c0 = sw2[(nq + r) * 2 + 0];
        float w2c1 = sw2[(nq + r) * 2 + 1];
        #pragma unroll
        for (int mt = 0; mt < 2; ++mt){
          float x  = hacc[nt][mt][r] + bb[r];
          float gv = gelu_f(x);
          lacc[mt][0] = __builtin_fmaf(gv, w2c0, lacc[mt][0]);
          lacc[mt][1] = __builtin_fmaf(gv, w2c1, lacc[mt][1]);
        }
      }
    }
  }

  int part = w * 4 + g;  // 0..31
  #pragma unroll
  for (int mt = 0; mt < 2; ++mt)
    #pragma unroll
    for (int c = 0; c < 2; ++c)
      sred[((16 * mt + l4) * 2 + c) * 32 + part] = lacc[mt][c];
  __syncthreads();
  if (tid < 64){
    int m = tid >> 1, c = tid & 1;
    float s = 0.f;
    #pragma unroll
    for (int p2 = 0; p2 < 32; ++p2) s += sred[(m * 2 + c) * 32 + p2];
    out[(size_t)(m0 + m) * 2 + c] = s + mb2[c];
  }
}

// ---- launch -----------------------------------------------------------------
extern "C" void kernel_launch(void* const* d_in, const int* in_sizes, int n_in,
                              void* d_out, int out_size, void* d_ws, size_t ws_size,
                              hipStream_t stream)
{
  const float* z0  = (const float*)d_in[0];
  const float* rW1 = (const float*)d_in[1];
  const float* rb1 = (const float*)d_in[2];
  const float* rW2 = (const float*)d_in[3];
  const float* rb2 = (const float*)d_in[4];
  const float* fW1 = (const float*)d_in[5];
  const float* fb1 = (const float*)d_in[6];
  const float* fW2 = (const float*)d_in[7];
  const float* fb2 = (const float*)d_in[8];
  const float* mW1 = (const float*)d_in[9];
  const float* mb1 = (const float*)d_in[10];
  const float* mW2 = (const float*)d_in[11];
  const float* mb2 = (const float*)d_in[12];
  float* out = (float*)d_out;

  char* ws = (char*)d_ws;
  short* w1t_all = (short*)(ws);                 //   524288 B (2 nets)
  short* w2t_all = (short*)(ws + 524288);        //   524288 B (2 nets)
  short* mw1t    = (short*)(ws + 1048576);       //  2097152 B
  short* proj    = (short*)(ws + 3145728);       // 16777216 B (real||fake, bf16)

  prep_kernel<<<768, 256, 0, stream>>>(rW1, rW2, fW1, fW2, mW1, w1t_all, w2t_all, mw1t);
  ode_kernel<<<256, 512, 0, stream>>>(z0, w1t_all, w2t_all,
                                      rW1, rb1, rb2, fW1, fb1, fb2, proj);
  cls_kernel<<<256, 512, 0, stream>>>(mw1t, proj, mb1, mW2, mb2, out);
}